// Round 14
// baseline (179.831 us; speedup 1.0000x reference)
//
#include <hip/hip_runtime.h>
#include <hip/hip_bf16.h>
#include <math.h>

// ---------------------------------------------------------------------------
// CausalSelfAttention: B=2, S=2048, D=1024, H=16, Hd=64. f32 in / f32 out.
// R29 = R28 (verified 174.0us: coset-balanced attn + gemm T1 + fused
// cvt_rope) with ONE isolated change: attn softmax P-conversion switched
// from truncation+masked-sum (48 VALU ops/thread/iter of plumbing) to RNE
// __float2bfloat16 + raw-f32 row-sum. Compiler emits hw v_cvt_pk_bf16_f32
// (m240: do NOT hand-write the asm). VALU is the busiest pipe (54%) after
// R28's balance fix, so this targets the marginal cost. Shipped in R20/R25
// bundled with regressions; correctness-proven (absmax 0.0234 < 0.068);
// never perf-isolated until now. Everything else byte-identical to R28.
// ---------------------------------------------------------------------------

typedef short bfrag __attribute__((ext_vector_type(8)));   // 8 bf16 = 4 VGPR
typedef float f32x4 __attribute__((ext_vector_type(4)));

__device__ __forceinline__ float bf2f(ushort u) {
    union { uint i; float f; } v; v.i = ((uint)u) << 16; return v.f;
}
__device__ __forceinline__ ushort f2bf(float f) {
    union { uint i; float f; } v; v.f = f;
    uint u = v.i;
    return (ushort)((u + 0x7fffu + ((u >> 16) & 1u)) >> 16);  // RNE
}
__device__ __forceinline__ ushort f2bf_hw(float f) {
    union { __hip_bfloat16 b; ushort u; } cv;
    cv.b = __float2bfloat16(f);                 // native cvt on gfx950 (RNE)
    return cv.u;
}

#define MFMA16 __builtin_amdgcn_mfma_f32_16x16x32_bf16

__device__ __forceinline__ void gl_lds16(const ushort* g, ushort* l) {
    __builtin_amdgcn_global_load_lds(
        (const __attribute__((address_space(1))) void*)g,
        (__attribute__((address_space(3))) void*)l, 16, 0, 0);
}

// ---------------------------------------------------------------------------
// Kernel 0: fused f32->bf16 convert + rope table.
// Blocks [0,3584): cvt (xb = x; wb = [Wq;Wkv]). Blocks [3584,3840): rope.
// ---------------------------------------------------------------------------
__global__ __launch_bounds__(256)
void cvt_rope(const float* __restrict__ x, const float* __restrict__ wq,
              const float* __restrict__ wkv, ushort* __restrict__ xb,
              ushort* __restrict__ wb, float2* __restrict__ tab)
{
    if (blockIdx.x >= 3584) {
        // rope table: tab[s][fi] = (cos,sin)(s * 10000^(-fi/32))
        int t  = ((int)blockIdx.x - 3584) * 256 + threadIdx.x;   // 65536
        int fi = t & 31, s = t >> 5;
        float invf = (float)exp((double)fi * -0.28782313662425574);
        float thf  = (float)s * invf;
        const double TWO_PI = 6.283185307179586476925287;
        double th = (double)thf;
        double kq = __builtin_rint(th * (1.0 / TWO_PI));
        float r = (float)(th - kq * TWO_PI);
        tab[t] = make_float2(cosf(r), sinf(r));
        return;
    }
    const size_t NX = 4096u * 1024u, NWQ = 1024u * 1024u;
    size_t i8 = ((size_t)blockIdx.x * 256 + threadIdx.x) * 8;
    const float* src;
    ushort* dst;
    if (i8 < NX) { src = x + i8; dst = xb + i8; }
    else {
        size_t j = i8 - NX;
        dst = wb + j;
        src = (j < NWQ) ? (wq + j) : (wkv + (j - NWQ));
    }
    float4 a = *(const float4*)(src);
    float4 c = *(const float4*)(src + 4);
    ushort u[8];
    u[0] = f2bf(a.x); u[1] = f2bf(a.y); u[2] = f2bf(a.z); u[3] = f2bf(a.w);
    u[4] = f2bf(c.x); u[5] = f2bf(c.y); u[6] = f2bf(c.z); u[7] = f2bf(c.w);
    *(uint4*)dst = *(uint4*)u;
}

// ---------------------------------------------------------------------------
// Kernel 1 (R26): QKV GEMM, BK=64, swizzled LDS, fused RoPE, T1 XCD swizzle.
// ---------------------------------------------------------------------------
__global__ __launch_bounds__(256)
void gemm_qkv(const ushort* __restrict__ xb, const ushort* __restrict__ wb,
              const float2* __restrict__ tab, ushort* __restrict__ Qb,
              ushort* __restrict__ Kb, ushort* __restrict__ Vt)
{
    __shared__ ushort Ash[128][64];
    __shared__ ushort Bsh[128][64];

    const int tid  = threadIdx.x;
    const int lane = tid & 63, wv = tid >> 6;
    const int quad = lane >> 4, li = lane & 15;

    // T1 XCD-aware remap: XCD c owns x' in [4c,4c+4), all y'
    const int lin  = (int)blockIdx.y * 32 + (int)blockIdx.x;
    const int lin2 = (lin & 7) * 96 + (lin >> 3);
    const int m0 = ((lin2 / 96) * 4 + (lin2 & 3)) * 128;
    const int n0 = ((lin2 % 96) >> 2) * 128;

    f32x4 acc[2][8];
#pragma unroll
    for (int mi = 0; mi < 2; mi++)
#pragma unroll
        for (int j = 0; j < 8; j++) acc[mi][j] = (f32x4){0.f, 0.f, 0.f, 0.f};

    const int r8  = lane >> 3;
    const int gch = ((lane & 7) ^ r8) * 8;
    const ushort* gA = xb + (size_t)(m0 + wv * 32 + r8) * 1024 + gch;
    const ushort* gB = wb + (size_t)(n0 + wv * 32 + r8) * 1024 + gch;

    for (int k0 = 0; k0 < 1024; k0 += 64) {
        __syncthreads();
#pragma unroll
        for (int c = 0; c < 4; c++) {
            gl_lds16(gA + (size_t)(c * 8) * 1024 + k0, &Ash[wv * 32 + c * 8][0]);
            gl_lds16(gB + (size_t)(c * 8) * 1024 + k0, &Bsh[wv * 32 + c * 8][0]);
        }
        __syncthreads();

        const int sw = li & 7;
#pragma unroll
        for (int ks = 0; ks < 2; ks++) {
            bfrag af[2], bf[8];
#pragma unroll
            for (int mi = 0; mi < 2; mi++)
                af[mi] = *(const bfrag*)
                    &Ash[wv * 32 + mi * 16 + li][(((ks << 2) | quad) ^ sw) * 8];
#pragma unroll
            for (int j = 0; j < 8; j++)
                bf[j] = *(const bfrag*)
                    &Bsh[j * 16 + li][(((ks << 2) | quad) ^ sw) * 8];
#pragma unroll
            for (int mi = 0; mi < 2; mi++)
#pragma unroll
                for (int j = 0; j < 8; j++)
                    acc[mi][j] = MFMA16(af[mi], bf[j], acc[mi][j], 0, 0, 0);
        }
    }

    if (n0 < 1024) {
        const int hbase = n0 >> 6;
#pragma unroll
        for (int mi = 0; mi < 2; mi++)
#pragma unroll
            for (int r = 0; r < 4; r++) {
                int m = m0 + wv * 32 + mi * 16 + quad * 4 + r;
                int bb = m >> 11, s = m & 2047;
                float2 t0 = tab[s * 32 + li];
                float2 t1 = tab[s * 32 + li + 16];
#pragma unroll
                for (int j = 0; j < 8; j++) {
                    float v  = acc[mi][j][r];
                    float vp = acc[mi][j ^ 2][r];
                    float2 tt = (j & 1) ? t1 : t0;
                    float rh = (j & 2) ? vp : -vp;
                    int h = hbase + (j >> 2), hd = (j & 3) * 16 + li;
                    Qb[(size_t)((bb * 16 + h) * 2048 + s) * 64 + hd] =
                        f2bf(v * tt.x + rh * tt.y);
                }
            }
    } else {
        const int h = (n0 - 1024) >> 7;
        const int li2 = li >> 1;
        if ((li & 1) == 0) {
#pragma unroll
            for (int mi = 0; mi < 2; mi++)
#pragma unroll
                for (int r = 0; r < 4; r++) {
                    int m = m0 + wv * 32 + mi * 16 + quad * 4 + r;
                    int bb = m >> 11, s = m & 2047;
                    float2 tt4[4];
#pragma unroll
                    for (int jj = 0; jj < 4; jj++)
                        tt4[jj] = tab[s * 32 + jj * 8 + li2];
#pragma unroll
                    for (int j = 0; j < 8; j++) {
                        float v  = acc[mi][j][r];
                        float vp = acc[mi][j ^ 4][r];
                        float2 tt = tt4[j & 3];
                        float rh = (j & 4) ? vp : -vp;
                        int hd = j * 8 + li2;
                        Kb[(size_t)((bb * 16 + h) * 2048 + s) * 64 + hd] =
                            f2bf(v * tt.x + rh * tt.y);
                    }
                }
        } else {
#pragma unroll
            for (int mi = 0; mi < 2; mi++) {
                int m4 = m0 + wv * 32 + mi * 16 + quad * 4;
                int bb = m4 >> 11, s0 = m4 & 2047;
#pragma unroll
                for (int j = 0; j < 8; j++) {
                    int hd = j * 8 + li2;
                    ushort u4[4];
#pragma unroll
                    for (int r = 0; r < 4; r++) u4[r] = f2bf(acc[mi][j][r]);
                    *(ushort4*)&Vt[(size_t)((bb * 16 + h) * 64 + hd) * 2048 + s0] =
                        *(ushort4*)u4;
                }
            }
        }
    }
}

// ---------------------------------------------------------------------------
// Kernel 2 (R28 attn + R29 RNE softmax): causal flash attention, swapped-QK^T
// in-register softmax. 1 WG (256 thr) = (b,h) x 64-row Q-tile; wave w owns
// 16 rows (q = li). Coset-balanced qt: u=(x+y)&31 -> {j,15-j,16+j,31-j};
// per-CU work = 66 exactly. Two-barrier staging with register prefetch.
// P via hw RNE cvt (__float2bfloat16) + raw-f32 row-sum.
// ---------------------------------------------------------------------------
__global__ __launch_bounds__(256)
void attn(const ushort* __restrict__ Qb, const ushort* __restrict__ Kb,
          const ushort* __restrict__ Vt, float* __restrict__ out)
{
    __shared__ ushort Ksh[64][72];
    __shared__ ushort Vsh[64][72];
    __shared__ ushort Psh[4][16][72];

    const int tid  = threadIdx.x;
    const int lane = tid & 63, w = tid >> 6;
    const int quad = lane >> 4, li = lane & 15;

    // coset-balanced q-tile assignment
    const int u  = ((int)blockIdx.x + (int)blockIdx.y) & 31;
    const int cj = u & 7, ci = u >> 3;
    const int qt = (ci == 0) ? cj : (ci == 1) ? (15 - cj)
                 : (ci == 2) ? (16 + cj) : (31 - cj);

    const int bh = blockIdx.y;
    const int b = bh >> 4, h = bh & 15;

    const int qrow = qt * 64 + w * 16 + li;      // this lane's q (swapped layout)
    const ushort* qp = Qb + (size_t)(bh * 2048 + qrow) * 64;
    bfrag qa0 = *(const bfrag*)(qp + quad * 8);
    bfrag qa1 = *(const bfrag*)(qp + quad * 8 + 32);

    f32x4 o[4];
#pragma unroll
    for (int j = 0; j < 4; j++) o[j] = (f32x4){0.f, 0.f, 0.f, 0.f};
    float lrow = 0.f;                            // running denom for q = li

    const int srow = tid >> 2, sc0 = (tid & 3) * 16;
    const ushort* kbase = Kb + (size_t)bh * 2048 * 64;
    const ushort* vbase = Vt + (size_t)bh * 64 * 2048;

    // preload kt=0 (16 VGPRs of prefetch state — no spill at this size)
    uint4 ka, kb_, va, vb_;
    {
        const ushort* gk = kbase + (size_t)srow * 64 + sc0;
        ka  = *(const uint4*)gk;
        kb_ = *(const uint4*)(gk + 8);
        const ushort* gv = vbase + (size_t)srow * 2048 + sc0;
        va  = *(const uint4*)gv;
        vb_ = *(const uint4*)(gv + 8);
    }

    const float C = 0.125f * 1.4426950408889634f;   // scale * log2(e)

    for (int kt = 0; kt <= qt; ++kt) {
        __syncthreads();
        *(uint4*)&Ksh[srow][sc0]     = ka;
        *(uint4*)&Ksh[srow][sc0 + 8] = kb_;
        *(uint4*)&Vsh[srow][sc0]     = va;
        *(uint4*)&Vsh[srow][sc0 + 8] = vb_;
        __syncthreads();

        if (kt < qt) {     // prefetch next tile; latency hidden by compute
            const ushort* gk = kbase + (size_t)((kt + 1) * 64 + srow) * 64 + sc0;
            ka  = *(const uint4*)gk;
            kb_ = *(const uint4*)(gk + 8);
            const ushort* gv = vbase + (size_t)srow * 2048 + (kt + 1) * 64 + sc0;
            va  = *(const uint4*)gv;
            vb_ = *(const uint4*)(gv + 8);
        }

        // --- scores, swapped: sc[j][r] = S[k = kt*64+j*16+quad*4+r][q = li] ---
        f32x4 sc[4];
        __builtin_amdgcn_s_setprio(1);
#pragma unroll
        for (int j = 0; j < 4; j++) {
            bfrag kb0 = *(const bfrag*)&Ksh[j * 16 + li][quad * 8];
            bfrag kb1 = *(const bfrag*)&Ksh[j * 16 + li][quad * 8 + 32];
            f32x4 z = (f32x4){0.f, 0.f, 0.f, 0.f};
            z = MFMA16(kb0, qa0, z, 0, 0, 0);
            z = MFMA16(kb1, qa1, z, 0, 0, 0);
            sc[j] = z;
        }
        __builtin_amdgcn_s_setprio(0);

        // --- causal mask: only the diagonal tile needs it ---
        if (kt == qt) {
#pragma unroll
            for (int j = 0; j < 4; j++) {
                int kg0 = kt * 64 + j * 16 + quad * 4;
#pragma unroll
                for (int r = 0; r < 4; r++)
                    sc[j][r] = (kg0 + r <= qrow) ? sc[j][r] : -3.0e38f;
            }
        }

        // --- P = exp2(sc*C), hw RNE to bf16; raw-f32 row-sum (R29) ---
        float rs = 0.f;
#pragma unroll
        for (int j = 0; j < 4; j++) {
            ushort pk[4];
#pragma unroll
            for (int r = 0; r < 4; r++) {
                float pv = exp2f(sc[j][r] * C);
                rs += pv;
                pk[r] = f2bf_hw(pv);
            }
            *(ushort4*)&Psh[w][li][j * 16 + quad * 4] = *(ushort4*)pk;
        }
        // complete row-sum for q=li across the 4 quads
        rs += __shfl_xor(rs, 16);
        rs += __shfl_xor(rs, 32);
        lrow += rs;

        // --- P: LDS -> A-fragment (wave-private Psh) ---
        asm volatile("s_waitcnt lgkmcnt(0)" ::: "memory");
        bfrag pa0 = *(const bfrag*)&Psh[w][li][quad * 8];
        bfrag pa1 = *(const bfrag*)&Psh[w][li][quad * 8 + 32];

        __builtin_amdgcn_s_setprio(1);
#pragma unroll
        for (int j = 0; j < 4; j++) {
            bfrag vb0 = *(const bfrag*)&Vsh[j * 16 + li][quad * 8];
            bfrag vb1 = *(const bfrag*)&Vsh[j * 16 + li][quad * 8 + 32];
            o[j] = MFMA16(pa0, vb0, o[j], 0, 0, 0);
            o[j] = MFMA16(pa1, vb1, o[j], 0, 0, 0);
        }
        __builtin_amdgcn_s_setprio(0);
    }

    // epilogue: redistribute l (held at lane li == q) to q = quad*4+r
    float lf[4];
#pragma unroll
    for (int r = 0; r < 4; r++)
        lf[r] = __shfl(lrow, (lane & 48) + quad * 4 + r);

#pragma unroll
    for (int j = 0; j < 4; j++)
#pragma unroll
        for (int r = 0; r < 4; r++) {
            int s = qt * 64 + w * 16 + quad * 4 + r;
            out[(size_t)(b * 2048 + s) * 1024 + h * 64 + j * 16 + li] =
                o[j][r] / lf[r];
        }
}

// ---------------------------------------------------------------------------
extern "C" void kernel_launch(void* const* d_in, const int* in_sizes, int n_in,
                              void* d_out, int out_size, void* d_ws, size_t ws_size,
                              hipStream_t stream)
{
    (void)in_sizes; (void)n_in; (void)out_size; (void)ws_size;
    const float* x   = (const float*)d_in[0];   // (2,2048,1024) f32
    const float* wq  = (const float*)d_in[1];   // (1024,1024)  f32
    const float* wkv = (const float*)d_in[2];   // (2048,1024)  f32
    // d_in[3] = causal mask — computed analytically

    ushort* xb = (ushort*)d_ws;                       // 4096x1024 bf16
    ushort* wb = xb + (size_t)4096 * 1024;            // 3072x1024 bf16
    float2* tab = (float2*)(wb + (size_t)3072 * 1024); // 2048x32 (cos,sin)
    ushort* Qb = (ushort*)(tab + 65536);              // (B,H,S,Hd)
    ushort* Kb = Qb + (size_t)2 * 16 * 2048 * 64;     // (B,H,S,Hd)
    ushort* Vt = Kb + (size_t)2 * 16 * 2048 * 64;     // (B,H,Hd,S)
    float* out = (float*)d_out;                       // f32 output

    cvt_rope<<<3840, 256, 0, stream>>>(x, wq, wkv, xb, wb, tab);
    dim3 g1(32, 24);
    gemm_qkv<<<g1, 256, 0, stream>>>(xb, wb, tab, Qb, Kb, Vt);
    dim3 g4(32, 32);
    attn<<<g4, 256, 0, stream>>>(Qb, Kb, Vt, out);
}

// Round 15
// 173.149 us; speedup vs baseline: 1.0386x; 1.0386x over previous
//
#include <hip/hip_runtime.h>
#include <hip/hip_bf16.h>
#include <math.h>

// ---------------------------------------------------------------------------
// CausalSelfAttention: B=2, S=2048, D=1024, H=16, Hd=64. f32 in / f32 out.
// R30 = R29 (attn 52.3us: coset balance + RNE softmax; gemm T1; fused
// cvt_rope) + two VALU->MFMA offloads in attn (VALU 48.6% vs MFMA 12.8%):
//  1. softmax scale C folded into Q at the gemm RoPE epilogue (f32 mul
//     before bf16 round; commutes with rotation) -- kills 16 v_mul/iter/thr.
//  2. row-sum l via ONES-column MFMA: lacc = MFMA16(pa, ones, lacc) sums
//     P over k on the matrix pipe. C/D layout puts l for q=quad*4+r in
//     reg r -- exactly the epilogue's lf[r], so the 2 shfl_xor/iter (DS
//     bpermutes) AND 4 epilogue shfls go away. l = sum of ROUNDED P
//     (consistent-with-P, R17-style) -> absmax likely back to 0.0156.
// No sync/layout/staging changes. Everything else byte-identical to R29.
// ---------------------------------------------------------------------------

typedef short bfrag __attribute__((ext_vector_type(8)));   // 8 bf16 = 4 VGPR
typedef float f32x4 __attribute__((ext_vector_type(4)));

__device__ __forceinline__ float bf2f(ushort u) {
    union { uint i; float f; } v; v.i = ((uint)u) << 16; return v.f;
}
__device__ __forceinline__ ushort f2bf(float f) {
    union { uint i; float f; } v; v.f = f;
    uint u = v.i;
    return (ushort)((u + 0x7fffu + ((u >> 16) & 1u)) >> 16);  // RNE
}
__device__ __forceinline__ ushort f2bf_hw(float f) {
    union { __hip_bfloat16 b; ushort u; } cv;
    cv.b = __float2bfloat16(f);                 // native cvt on gfx950 (RNE)
    return cv.u;
}

#define MFMA16 __builtin_amdgcn_mfma_f32_16x16x32_bf16

__device__ __forceinline__ void gl_lds16(const ushort* g, ushort* l) {
    __builtin_amdgcn_global_load_lds(
        (const __attribute__((address_space(1))) void*)g,
        (__attribute__((address_space(3))) void*)l, 16, 0, 0);
}

// ---------------------------------------------------------------------------
// Kernel 0: fused f32->bf16 convert + rope table.
// Blocks [0,3584): cvt (xb = x; wb = [Wq;Wkv]). Blocks [3584,3840): rope.
// ---------------------------------------------------------------------------
__global__ __launch_bounds__(256)
void cvt_rope(const float* __restrict__ x, const float* __restrict__ wq,
              const float* __restrict__ wkv, ushort* __restrict__ xb,
              ushort* __restrict__ wb, float2* __restrict__ tab)
{
    if (blockIdx.x >= 3584) {
        // rope table: tab[s][fi] = (cos,sin)(s * 10000^(-fi/32))
        int t  = ((int)blockIdx.x - 3584) * 256 + threadIdx.x;   // 65536
        int fi = t & 31, s = t >> 5;
        float invf = (float)exp((double)fi * -0.28782313662425574);
        float thf  = (float)s * invf;
        const double TWO_PI = 6.283185307179586476925287;
        double th = (double)thf;
        double kq = __builtin_rint(th * (1.0 / TWO_PI));
        float r = (float)(th - kq * TWO_PI);
        tab[t] = make_float2(cosf(r), sinf(r));
        return;
    }
    const size_t NX = 4096u * 1024u, NWQ = 1024u * 1024u;
    size_t i8 = ((size_t)blockIdx.x * 256 + threadIdx.x) * 8;
    const float* src;
    ushort* dst;
    if (i8 < NX) { src = x + i8; dst = xb + i8; }
    else {
        size_t j = i8 - NX;
        dst = wb + j;
        src = (j < NWQ) ? (wq + j) : (wkv + (j - NWQ));
    }
    float4 a = *(const float4*)(src);
    float4 c = *(const float4*)(src + 4);
    ushort u[8];
    u[0] = f2bf(a.x); u[1] = f2bf(a.y); u[2] = f2bf(a.z); u[3] = f2bf(a.w);
    u[4] = f2bf(c.x); u[5] = f2bf(c.y); u[6] = f2bf(c.z); u[7] = f2bf(c.w);
    *(uint4*)dst = *(uint4*)u;
}

// ---------------------------------------------------------------------------
// Kernel 1 (R26 + R30 C-fold): QKV GEMM, BK=64, swizzled LDS, fused RoPE,
// T1 XCD swizzle. Q-epilogue multiplies by C = 0.125*log2(e) in f32 before
// the bf16 round (scores arrive pre-scaled in attn).
// ---------------------------------------------------------------------------
__global__ __launch_bounds__(256)
void gemm_qkv(const ushort* __restrict__ xb, const ushort* __restrict__ wb,
              const float2* __restrict__ tab, ushort* __restrict__ Qb,
              ushort* __restrict__ Kb, ushort* __restrict__ Vt)
{
    __shared__ ushort Ash[128][64];
    __shared__ ushort Bsh[128][64];

    const int tid  = threadIdx.x;
    const int lane = tid & 63, wv = tid >> 6;
    const int quad = lane >> 4, li = lane & 15;

    // T1 XCD-aware remap: XCD c owns x' in [4c,4c+4), all y'
    const int lin  = (int)blockIdx.y * 32 + (int)blockIdx.x;
    const int lin2 = (lin & 7) * 96 + (lin >> 3);
    const int m0 = ((lin2 / 96) * 4 + (lin2 & 3)) * 128;
    const int n0 = ((lin2 % 96) >> 2) * 128;

    f32x4 acc[2][8];
#pragma unroll
    for (int mi = 0; mi < 2; mi++)
#pragma unroll
        for (int j = 0; j < 8; j++) acc[mi][j] = (f32x4){0.f, 0.f, 0.f, 0.f};

    const int r8  = lane >> 3;
    const int gch = ((lane & 7) ^ r8) * 8;
    const ushort* gA = xb + (size_t)(m0 + wv * 32 + r8) * 1024 + gch;
    const ushort* gB = wb + (size_t)(n0 + wv * 32 + r8) * 1024 + gch;

    for (int k0 = 0; k0 < 1024; k0 += 64) {
        __syncthreads();
#pragma unroll
        for (int c = 0; c < 4; c++) {
            gl_lds16(gA + (size_t)(c * 8) * 1024 + k0, &Ash[wv * 32 + c * 8][0]);
            gl_lds16(gB + (size_t)(c * 8) * 1024 + k0, &Bsh[wv * 32 + c * 8][0]);
        }
        __syncthreads();

        const int sw = li & 7;
#pragma unroll
        for (int ks = 0; ks < 2; ks++) {
            bfrag af[2], bf[8];
#pragma unroll
            for (int mi = 0; mi < 2; mi++)
                af[mi] = *(const bfrag*)
                    &Ash[wv * 32 + mi * 16 + li][(((ks << 2) | quad) ^ sw) * 8];
#pragma unroll
            for (int j = 0; j < 8; j++)
                bf[j] = *(const bfrag*)
                    &Bsh[j * 16 + li][(((ks << 2) | quad) ^ sw) * 8];
#pragma unroll
            for (int mi = 0; mi < 2; mi++)
#pragma unroll
                for (int j = 0; j < 8; j++)
                    acc[mi][j] = MFMA16(af[mi], bf[j], acc[mi][j], 0, 0, 0);
        }
    }

    if (n0 < 1024) {
        const float CS = 0.125f * 1.4426950408889634f;   // folded softmax scale
        const int hbase = n0 >> 6;
#pragma unroll
        for (int mi = 0; mi < 2; mi++)
#pragma unroll
            for (int r = 0; r < 4; r++) {
                int m = m0 + wv * 32 + mi * 16 + quad * 4 + r;
                int bb = m >> 11, s = m & 2047;
                float2 t0 = tab[s * 32 + li];
                float2 t1 = tab[s * 32 + li + 16];
#pragma unroll
                for (int j = 0; j < 8; j++) {
                    float v  = acc[mi][j][r];
                    float vp = acc[mi][j ^ 2][r];
                    float2 tt = (j & 1) ? t1 : t0;
                    float rh = (j & 2) ? vp : -vp;
                    int h = hbase + (j >> 2), hd = (j & 3) * 16 + li;
                    Qb[(size_t)((bb * 16 + h) * 2048 + s) * 64 + hd] =
                        f2bf((v * tt.x + rh * tt.y) * CS);
                }
            }
    } else {
        const int h = (n0 - 1024) >> 7;
        const int li2 = li >> 1;
        if ((li & 1) == 0) {
#pragma unroll
            for (int mi = 0; mi < 2; mi++)
#pragma unroll
                for (int r = 0; r < 4; r++) {
                    int m = m0 + wv * 32 + mi * 16 + quad * 4 + r;
                    int bb = m >> 11, s = m & 2047;
                    float2 tt4[4];
#pragma unroll
                    for (int jj = 0; jj < 4; jj++)
                        tt4[jj] = tab[s * 32 + jj * 8 + li2];
#pragma unroll
                    for (int j = 0; j < 8; j++) {
                        float v  = acc[mi][j][r];
                        float vp = acc[mi][j ^ 4][r];
                        float2 tt = tt4[j & 3];
                        float rh = (j & 4) ? vp : -vp;
                        int hd = j * 8 + li2;
                        Kb[(size_t)((bb * 16 + h) * 2048 + s) * 64 + hd] =
                            f2bf(v * tt.x + rh * tt.y);
                    }
                }
        } else {
#pragma unroll
            for (int mi = 0; mi < 2; mi++) {
                int m4 = m0 + wv * 32 + mi * 16 + quad * 4;
                int bb = m4 >> 11, s0 = m4 & 2047;
#pragma unroll
                for (int j = 0; j < 8; j++) {
                    int hd = j * 8 + li2;
                    ushort u4[4];
#pragma unroll
                    for (int r = 0; r < 4; r++) u4[r] = f2bf(acc[mi][j][r]);
                    *(ushort4*)&Vt[(size_t)((bb * 16 + h) * 64 + hd) * 2048 + s0] =
                        *(ushort4*)u4;
                }
            }
        }
    }
}

// ---------------------------------------------------------------------------
// Kernel 2 (R30): causal flash attention, swapped-QK^T. Coset-balanced qt;
// two-barrier staging with register prefetch. Q arrives pre-scaled by C, so
// P = exp2(sc) directly. Row-sum l computed on the MFMA pipe via ones-column
// (lacc = P x ones): reg r holds l for q=quad*4+r -- no shfl redistribution.
// ---------------------------------------------------------------------------
__global__ __launch_bounds__(256)
void attn(const ushort* __restrict__ Qb, const ushort* __restrict__ Kb,
          const ushort* __restrict__ Vt, float* __restrict__ out)
{
    __shared__ ushort Ksh[64][72];
    __shared__ ushort Vsh[64][72];
    __shared__ ushort Psh[4][16][72];

    const int tid  = threadIdx.x;
    const int lane = tid & 63, w = tid >> 6;
    const int quad = lane >> 4, li = lane & 15;

    // coset-balanced q-tile assignment
    const int u  = ((int)blockIdx.x + (int)blockIdx.y) & 31;
    const int cj = u & 7, ci = u >> 3;
    const int qt = (ci == 0) ? cj : (ci == 1) ? (15 - cj)
                 : (ci == 2) ? (16 + cj) : (31 - cj);

    const int bh = blockIdx.y;
    const int b = bh >> 4, h = bh & 15;

    const int qrow = qt * 64 + w * 16 + li;      // this lane's q (swapped layout)
    const ushort* qp = Qb + (size_t)(bh * 2048 + qrow) * 64;
    bfrag qa0 = *(const bfrag*)(qp + quad * 8);
    bfrag qa1 = *(const bfrag*)(qp + quad * 8 + 32);

    // ones B-fragment (bf16 1.0 = 0x3F80) for the l-sum MFMA
    union { ushort s[8]; bfrag f; } onesu;
#pragma unroll
    for (int i = 0; i < 8; i++) onesu.s[i] = 0x3F80;
    const bfrag ones = onesu.f;

    f32x4 o[4];
#pragma unroll
    for (int j = 0; j < 4; j++) o[j] = (f32x4){0.f, 0.f, 0.f, 0.f};
    f32x4 lacc = (f32x4){0.f, 0.f, 0.f, 0.f};   // l for q=quad*4+r in reg r

    const int srow = tid >> 2, sc0 = (tid & 3) * 16;
    const ushort* kbase = Kb + (size_t)bh * 2048 * 64;
    const ushort* vbase = Vt + (size_t)bh * 64 * 2048;

    // preload kt=0 (16 VGPRs of prefetch state — no spill at this size)
    uint4 ka, kb_, va, vb_;
    {
        const ushort* gk = kbase + (size_t)srow * 64 + sc0;
        ka  = *(const uint4*)gk;
        kb_ = *(const uint4*)(gk + 8);
        const ushort* gv = vbase + (size_t)srow * 2048 + sc0;
        va  = *(const uint4*)gv;
        vb_ = *(const uint4*)(gv + 8);
    }

    for (int kt = 0; kt <= qt; ++kt) {
        __syncthreads();
        *(uint4*)&Ksh[srow][sc0]     = ka;
        *(uint4*)&Ksh[srow][sc0 + 8] = kb_;
        *(uint4*)&Vsh[srow][sc0]     = va;
        *(uint4*)&Vsh[srow][sc0 + 8] = vb_;
        __syncthreads();

        if (kt < qt) {     // prefetch next tile; latency hidden by compute
            const ushort* gk = kbase + (size_t)((kt + 1) * 64 + srow) * 64 + sc0;
            ka  = *(const uint4*)gk;
            kb_ = *(const uint4*)(gk + 8);
            const ushort* gv = vbase + (size_t)srow * 2048 + (kt + 1) * 64 + sc0;
            va  = *(const uint4*)gv;
            vb_ = *(const uint4*)(gv + 8);
        }

        // --- scores (pre-scaled): sc[j][r] = C*S[k=kt*64+j*16+quad*4+r][q=li] ---
        f32x4 sc[4];
        __builtin_amdgcn_s_setprio(1);
#pragma unroll
        for (int j = 0; j < 4; j++) {
            bfrag kb0 = *(const bfrag*)&Ksh[j * 16 + li][quad * 8];
            bfrag kb1 = *(const bfrag*)&Ksh[j * 16 + li][quad * 8 + 32];
            f32x4 z = (f32x4){0.f, 0.f, 0.f, 0.f};
            z = MFMA16(kb0, qa0, z, 0, 0, 0);
            z = MFMA16(kb1, qa1, z, 0, 0, 0);
            sc[j] = z;
        }
        __builtin_amdgcn_s_setprio(0);

        // --- causal mask: only the diagonal tile needs it ---
        if (kt == qt) {
#pragma unroll
            for (int j = 0; j < 4; j++) {
                int kg0 = kt * 64 + j * 16 + quad * 4;
#pragma unroll
                for (int r = 0; r < 4; r++)
                    sc[j][r] = (kg0 + r <= qrow) ? sc[j][r] : -3.0e38f;
            }
        }

        // --- P = exp2(sc), hw RNE to bf16 (no separate row-sum: MFMA does it) ---
#pragma unroll
        for (int j = 0; j < 4; j++) {
            ushort pk[4];
#pragma unroll
            for (int r = 0; r < 4; r++)
                pk[r] = f2bf_hw(exp2f(sc[j][r]));
            *(ushort4*)&Psh[w][li][j * 16 + quad * 4] = *(ushort4*)pk;
        }

        // --- P: LDS -> A-fragment (wave-private Psh) ---
        asm volatile("s_waitcnt lgkmcnt(0)" ::: "memory");
        bfrag pa0 = *(const bfrag*)&Psh[w][li][quad * 8];
        bfrag pa1 = *(const bfrag*)&Psh[w][li][quad * 8 + 32];

        __builtin_amdgcn_s_setprio(1);
#pragma unroll
        for (int j = 0; j < 4; j++) {
            bfrag vb0 = *(const bfrag*)&Vsh[j * 16 + li][quad * 8];
            bfrag vb1 = *(const bfrag*)&Vsh[j * 16 + li][quad * 8 + 32];
            o[j] = MFMA16(pa0, vb0, o[j], 0, 0, 0);
            o[j] = MFMA16(pa1, vb1, o[j], 0, 0, 0);
        }
        // l-sum on the matrix pipe: lacc[r] += sum_k P[k][q=quad*4+r]
        lacc = MFMA16(pa0, ones, lacc, 0, 0, 0);
        lacc = MFMA16(pa1, ones, lacc, 0, 0, 0);
        __builtin_amdgcn_s_setprio(0);
    }

    // epilogue: lacc[r] IS l for q = quad*4+r (C/D layout row = quad*4+reg)
#pragma unroll
    for (int j = 0; j < 4; j++)
#pragma unroll
        for (int r = 0; r < 4; r++) {
            int s = qt * 64 + w * 16 + quad * 4 + r;
            out[(size_t)(b * 2048 + s) * 1024 + h * 64 + j * 16 + li] =
                o[j][r] / lacc[r];
        }
}

// ---------------------------------------------------------------------------
extern "C" void kernel_launch(void* const* d_in, const int* in_sizes, int n_in,
                              void* d_out, int out_size, void* d_ws, size_t ws_size,
                              hipStream_t stream)
{
    (void)in_sizes; (void)n_in; (void)out_size; (void)ws_size;
    const float* x   = (const float*)d_in[0];   // (2,2048,1024) f32
    const float* wq  = (const float*)d_in[1];   // (1024,1024)  f32
    const float* wkv = (const float*)d_in[2];   // (2048,1024)  f32
    // d_in[3] = causal mask — computed analytically

    ushort* xb = (ushort*)d_ws;                       // 4096x1024 bf16
    ushort* wb = xb + (size_t)4096 * 1024;            // 3072x1024 bf16
    float2* tab = (float2*)(wb + (size_t)3072 * 1024); // 2048x32 (cos,sin)
    ushort* Qb = (ushort*)(tab + 65536);              // (B,H,S,Hd) pre-scaled by C
    ushort* Kb = Qb + (size_t)2 * 16 * 2048 * 64;     // (B,H,S,Hd)
    ushort* Vt = Kb + (size_t)2 * 16 * 2048 * 64;     // (B,H,Hd,S)
    float* out = (float*)d_out;                       // f32 output

    cvt_rope<<<3840, 256, 0, stream>>>(x, wq, wkv, xb, wb, tab);
    dim3 g1(32, 24);
    gemm_qkv<<<g1, 256, 0, stream>>>(xb, wb, tab, Qb, Kb, Vt);
    dim3 g4(32, 32);
    attn<<<g4, 256, 0, stream>>>(Qb, Kb, Vt, out);
}

// Round 16
// 172.377 us; speedup vs baseline: 1.0432x; 1.0045x over previous
//
#include <hip/hip_runtime.h>
#include <hip/hip_bf16.h>
#include <math.h>

// ---------------------------------------------------------------------------
// CausalSelfAttention: B=2, S=2048, D=1024, H=16, Hd=64. f32 in / f32 out.
// R31 = R30 (attn 48.9us: coset balance + RNE softmax + ones-MFMA l-sum +
// C-fold; gemm T1; fused cvt_rope) + attn HEAD->XCD/CU pinning:
// bh = (lin&7)*4 + ((lin>>3)&3), u = lin>>5. Co-resident blocks {lin,+256,
// +512,+768} share the SAME bh (terms invariant) and get qt coset
// {u,u+8,u+16,u+24} -> sigma -> per-CU work = 66 exactly (R28 invariant
// preserved). Each XCD owns 4 heads (2MB KV < 4MB L2, was 16MB over all
// XCDs -> thrash, FETCH 62.5MB ~ 4x KV refetch); the 4 blocks per CU
// stream the same head -> each KV tile HBM-fetched once, L2-hit x3.
// Plus: prefetch addresses -> incremented pointers (kills per-iter mul
// chains; VALU-observable). No math/sync/layout changes.
// ---------------------------------------------------------------------------

typedef short bfrag __attribute__((ext_vector_type(8)));   // 8 bf16 = 4 VGPR
typedef float f32x4 __attribute__((ext_vector_type(4)));

__device__ __forceinline__ float bf2f(ushort u) {
    union { uint i; float f; } v; v.i = ((uint)u) << 16; return v.f;
}
__device__ __forceinline__ ushort f2bf(float f) {
    union { uint i; float f; } v; v.f = f;
    uint u = v.i;
    return (ushort)((u + 0x7fffu + ((u >> 16) & 1u)) >> 16);  // RNE
}
__device__ __forceinline__ ushort f2bf_hw(float f) {
    union { __hip_bfloat16 b; ushort u; } cv;
    cv.b = __float2bfloat16(f);                 // native cvt on gfx950 (RNE)
    return cv.u;
}

#define MFMA16 __builtin_amdgcn_mfma_f32_16x16x32_bf16

__device__ __forceinline__ void gl_lds16(const ushort* g, ushort* l) {
    __builtin_amdgcn_global_load_lds(
        (const __attribute__((address_space(1))) void*)g,
        (__attribute__((address_space(3))) void*)l, 16, 0, 0);
}

// ---------------------------------------------------------------------------
// Kernel 0: fused f32->bf16 convert + rope table.
// Blocks [0,3584): cvt (xb = x; wb = [Wq;Wkv]). Blocks [3584,3840): rope.
// ---------------------------------------------------------------------------
__global__ __launch_bounds__(256)
void cvt_rope(const float* __restrict__ x, const float* __restrict__ wq,
              const float* __restrict__ wkv, ushort* __restrict__ xb,
              ushort* __restrict__ wb, float2* __restrict__ tab)
{
    if (blockIdx.x >= 3584) {
        // rope table: tab[s][fi] = (cos,sin)(s * 10000^(-fi/32))
        int t  = ((int)blockIdx.x - 3584) * 256 + threadIdx.x;   // 65536
        int fi = t & 31, s = t >> 5;
        float invf = (float)exp((double)fi * -0.28782313662425574);
        float thf  = (float)s * invf;
        const double TWO_PI = 6.283185307179586476925287;
        double th = (double)thf;
        double kq = __builtin_rint(th * (1.0 / TWO_PI));
        float r = (float)(th - kq * TWO_PI);
        tab[t] = make_float2(cosf(r), sinf(r));
        return;
    }
    const size_t NX = 4096u * 1024u, NWQ = 1024u * 1024u;
    size_t i8 = ((size_t)blockIdx.x * 256 + threadIdx.x) * 8;
    const float* src;
    ushort* dst;
    if (i8 < NX) { src = x + i8; dst = xb + i8; }
    else {
        size_t j = i8 - NX;
        dst = wb + j;
        src = (j < NWQ) ? (wq + j) : (wkv + (j - NWQ));
    }
    float4 a = *(const float4*)(src);
    float4 c = *(const float4*)(src + 4);
    ushort u[8];
    u[0] = f2bf(a.x); u[1] = f2bf(a.y); u[2] = f2bf(a.z); u[3] = f2bf(a.w);
    u[4] = f2bf(c.x); u[5] = f2bf(c.y); u[6] = f2bf(c.z); u[7] = f2bf(c.w);
    *(uint4*)dst = *(uint4*)u;
}

// ---------------------------------------------------------------------------
// Kernel 1 (R26 + R30 C-fold): QKV GEMM, BK=64, swizzled LDS, fused RoPE,
// T1 XCD swizzle. Q-epilogue multiplies by C = 0.125*log2(e) in f32 before
// the bf16 round (scores arrive pre-scaled in attn).
// ---------------------------------------------------------------------------
__global__ __launch_bounds__(256)
void gemm_qkv(const ushort* __restrict__ xb, const ushort* __restrict__ wb,
              const float2* __restrict__ tab, ushort* __restrict__ Qb,
              ushort* __restrict__ Kb, ushort* __restrict__ Vt)
{
    __shared__ ushort Ash[128][64];
    __shared__ ushort Bsh[128][64];

    const int tid  = threadIdx.x;
    const int lane = tid & 63, wv = tid >> 6;
    const int quad = lane >> 4, li = lane & 15;

    // T1 XCD-aware remap: XCD c owns x' in [4c,4c+4), all y'
    const int lin  = (int)blockIdx.y * 32 + (int)blockIdx.x;
    const int lin2 = (lin & 7) * 96 + (lin >> 3);
    const int m0 = ((lin2 / 96) * 4 + (lin2 & 3)) * 128;
    const int n0 = ((lin2 % 96) >> 2) * 128;

    f32x4 acc[2][8];
#pragma unroll
    for (int mi = 0; mi < 2; mi++)
#pragma unroll
        for (int j = 0; j < 8; j++) acc[mi][j] = (f32x4){0.f, 0.f, 0.f, 0.f};

    const int r8  = lane >> 3;
    const int gch = ((lane & 7) ^ r8) * 8;
    const ushort* gA = xb + (size_t)(m0 + wv * 32 + r8) * 1024 + gch;
    const ushort* gB = wb + (size_t)(n0 + wv * 32 + r8) * 1024 + gch;

    for (int k0 = 0; k0 < 1024; k0 += 64) {
        __syncthreads();
#pragma unroll
        for (int c = 0; c < 4; c++) {
            gl_lds16(gA + (size_t)(c * 8) * 1024 + k0, &Ash[wv * 32 + c * 8][0]);
            gl_lds16(gB + (size_t)(c * 8) * 1024 + k0, &Bsh[wv * 32 + c * 8][0]);
        }
        __syncthreads();

        const int sw = li & 7;
#pragma unroll
        for (int ks = 0; ks < 2; ks++) {
            bfrag af[2], bf[8];
#pragma unroll
            for (int mi = 0; mi < 2; mi++)
                af[mi] = *(const bfrag*)
                    &Ash[wv * 32 + mi * 16 + li][(((ks << 2) | quad) ^ sw) * 8];
#pragma unroll
            for (int j = 0; j < 8; j++)
                bf[j] = *(const bfrag*)
                    &Bsh[j * 16 + li][(((ks << 2) | quad) ^ sw) * 8];
#pragma unroll
            for (int mi = 0; mi < 2; mi++)
#pragma unroll
                for (int j = 0; j < 8; j++)
                    acc[mi][j] = MFMA16(af[mi], bf[j], acc[mi][j], 0, 0, 0);
        }
    }

    if (n0 < 1024) {
        const float CS = 0.125f * 1.4426950408889634f;   // folded softmax scale
        const int hbase = n0 >> 6;
#pragma unroll
        for (int mi = 0; mi < 2; mi++)
#pragma unroll
            for (int r = 0; r < 4; r++) {
                int m = m0 + wv * 32 + mi * 16 + quad * 4 + r;
                int bb = m >> 11, s = m & 2047;
                float2 t0 = tab[s * 32 + li];
                float2 t1 = tab[s * 32 + li + 16];
#pragma unroll
                for (int j = 0; j < 8; j++) {
                    float v  = acc[mi][j][r];
                    float vp = acc[mi][j ^ 2][r];
                    float2 tt = (j & 1) ? t1 : t0;
                    float rh = (j & 2) ? vp : -vp;
                    int h = hbase + (j >> 2), hd = (j & 3) * 16 + li;
                    Qb[(size_t)((bb * 16 + h) * 2048 + s) * 64 + hd] =
                        f2bf((v * tt.x + rh * tt.y) * CS);
                }
            }
    } else {
        const int h = (n0 - 1024) >> 7;
        const int li2 = li >> 1;
        if ((li & 1) == 0) {
#pragma unroll
            for (int mi = 0; mi < 2; mi++)
#pragma unroll
                for (int r = 0; r < 4; r++) {
                    int m = m0 + wv * 32 + mi * 16 + quad * 4 + r;
                    int bb = m >> 11, s = m & 2047;
                    float2 tt4[4];
#pragma unroll
                    for (int jj = 0; jj < 4; jj++)
                        tt4[jj] = tab[s * 32 + jj * 8 + li2];
#pragma unroll
                    for (int j = 0; j < 8; j++) {
                        float v  = acc[mi][j][r];
                        float vp = acc[mi][j ^ 4][r];
                        float2 tt = tt4[j & 3];
                        float rh = (j & 4) ? vp : -vp;
                        int hd = j * 8 + li2;
                        Kb[(size_t)((bb * 16 + h) * 2048 + s) * 64 + hd] =
                            f2bf(v * tt.x + rh * tt.y);
                    }
                }
        } else {
#pragma unroll
            for (int mi = 0; mi < 2; mi++) {
                int m4 = m0 + wv * 32 + mi * 16 + quad * 4;
                int bb = m4 >> 11, s0 = m4 & 2047;
#pragma unroll
                for (int j = 0; j < 8; j++) {
                    int hd = j * 8 + li2;
                    ushort u4[4];
#pragma unroll
                    for (int r = 0; r < 4; r++) u4[r] = f2bf(acc[mi][j][r]);
                    *(ushort4*)&Vt[(size_t)((bb * 16 + h) * 64 + hd) * 2048 + s0] =
                        *(ushort4*)u4;
                }
            }
        }
    }
}

// ---------------------------------------------------------------------------
// Kernel 2 (R31): causal flash attention, swapped-QK^T. Head->XCD/CU pinned:
// bh = (lin&7)*4 + ((lin>>3)&3) (same bh for co-resident blocks; 4 heads =
// 2MB KV per XCD L2); u = lin>>5 -> coset sigma -> per-CU work = 66 exactly.
// Q pre-scaled by C; P = exp2(sc); l via ones-column MFMA. Two-barrier
// staging with incremented-pointer register prefetch.
// ---------------------------------------------------------------------------
__global__ __launch_bounds__(256)
void attn(const ushort* __restrict__ Qb, const ushort* __restrict__ Kb,
          const ushort* __restrict__ Vt, float* __restrict__ out)
{
    __shared__ ushort Ksh[64][72];
    __shared__ ushort Vsh[64][72];
    __shared__ ushort Psh[4][16][72];

    const int tid  = threadIdx.x;
    const int lane = tid & 63, w = tid >> 6;
    const int quad = lane >> 4, li = lane & 15;

    // R31 head/XCD pinning + coset-balanced q-tile assignment
    const int lin = (int)blockIdx.y * 32 + (int)blockIdx.x;
    const int bh  = (lin & 7) * 4 + ((lin >> 3) & 3);
    const int u   = lin >> 5;
    const int cj = u & 7, ci = u >> 3;
    const int qt = (ci == 0) ? cj : (ci == 1) ? (15 - cj)
                 : (ci == 2) ? (16 + cj) : (31 - cj);

    const int b = bh >> 4, h = bh & 15;

    const int qrow = qt * 64 + w * 16 + li;      // this lane's q (swapped layout)
    const ushort* qp = Qb + (size_t)(bh * 2048 + qrow) * 64;
    bfrag qa0 = *(const bfrag*)(qp + quad * 8);
    bfrag qa1 = *(const bfrag*)(qp + quad * 8 + 32);

    // ones B-fragment (bf16 1.0 = 0x3F80) for the l-sum MFMA
    union { ushort s[8]; bfrag f; } onesu;
#pragma unroll
    for (int i = 0; i < 8; i++) onesu.s[i] = 0x3F80;
    const bfrag ones = onesu.f;

    f32x4 o[4];
#pragma unroll
    for (int j = 0; j < 4; j++) o[j] = (f32x4){0.f, 0.f, 0.f, 0.f};
    f32x4 lacc = (f32x4){0.f, 0.f, 0.f, 0.f};   // l for q=quad*4+r in reg r

    const int srow = tid >> 2, sc0 = (tid & 3) * 16;
    const ushort* kbase = Kb + (size_t)bh * 2048 * 64;
    const ushort* vbase = Vt + (size_t)bh * 64 * 2048;

    // preload kt=0; prefetch pointers advance incrementally (no per-iter mul)
    uint4 ka, kb_, va, vb_;
    const ushort* gkp = kbase + (size_t)(64 + srow) * 64 + sc0;      // tile 1 K
    const ushort* gvp = vbase + (size_t)srow * 2048 + 64 + sc0;      // tile 1 V
    {
        const ushort* gk = kbase + (size_t)srow * 64 + sc0;
        ka  = *(const uint4*)gk;
        kb_ = *(const uint4*)(gk + 8);
        const ushort* gv = vbase + (size_t)srow * 2048 + sc0;
        va  = *(const uint4*)gv;
        vb_ = *(const uint4*)(gv + 8);
    }

    for (int kt = 0; kt <= qt; ++kt) {
        __syncthreads();
        *(uint4*)&Ksh[srow][sc0]     = ka;
        *(uint4*)&Ksh[srow][sc0 + 8] = kb_;
        *(uint4*)&Vsh[srow][sc0]     = va;
        *(uint4*)&Vsh[srow][sc0 + 8] = vb_;
        __syncthreads();

        if (kt < qt) {     // prefetch next tile; latency hidden by compute
            ka  = *(const uint4*)gkp;
            kb_ = *(const uint4*)(gkp + 8);
            va  = *(const uint4*)gvp;
            vb_ = *(const uint4*)(gvp + 8);
            gkp += 64 * 64;          // next K tile (64 rows x 64 hd)
            gvp += 64;               // next V tile (64 s-cols)
        }

        // --- scores (pre-scaled): sc[j][r] = C*S[k=kt*64+j*16+quad*4+r][q=li] ---
        f32x4 sc[4];
        __builtin_amdgcn_s_setprio(1);
#pragma unroll
        for (int j = 0; j < 4; j++) {
            bfrag kb0 = *(const bfrag*)&Ksh[j * 16 + li][quad * 8];
            bfrag kb1 = *(const bfrag*)&Ksh[j * 16 + li][quad * 8 + 32];
            f32x4 z = (f32x4){0.f, 0.f, 0.f, 0.f};
            z = MFMA16(kb0, qa0, z, 0, 0, 0);
            z = MFMA16(kb1, qa1, z, 0, 0, 0);
            sc[j] = z;
        }
        __builtin_amdgcn_s_setprio(0);

        // --- causal mask: only the diagonal tile needs it ---
        if (kt == qt) {
#pragma unroll
            for (int j = 0; j < 4; j++) {
                int kg0 = kt * 64 + j * 16 + quad * 4;
#pragma unroll
                for (int r = 0; r < 4; r++)
                    sc[j][r] = (kg0 + r <= qrow) ? sc[j][r] : -3.0e38f;
            }
        }

        // --- P = exp2(sc), hw RNE to bf16 (row-sum done by ones-MFMA) ---
#pragma unroll
        for (int j = 0; j < 4; j++) {
            ushort pk[4];
#pragma unroll
            for (int r = 0; r < 4; r++)
                pk[r] = f2bf_hw(exp2f(sc[j][r]));
            *(ushort4*)&Psh[w][li][j * 16 + quad * 4] = *(ushort4*)pk;
        }

        // --- P: LDS -> A-fragment (wave-private Psh) ---
        asm volatile("s_waitcnt lgkmcnt(0)" ::: "memory");
        bfrag pa0 = *(const bfrag*)&Psh[w][li][quad * 8];
        bfrag pa1 = *(const bfrag*)&Psh[w][li][quad * 8 + 32];

        __builtin_amdgcn_s_setprio(1);
#pragma unroll
        for (int j = 0; j < 4; j++) {
            bfrag vb0 = *(const bfrag*)&Vsh[j * 16 + li][quad * 8];
            bfrag vb1 = *(const bfrag*)&Vsh[j * 16 + li][quad * 8 + 32];
            o[j] = MFMA16(pa0, vb0, o[j], 0, 0, 0);
            o[j] = MFMA16(pa1, vb1, o[j], 0, 0, 0);
        }
        // l-sum on the matrix pipe: lacc[r] += sum_k P[k][q=quad*4+r]
        lacc = MFMA16(pa0, ones, lacc, 0, 0, 0);
        lacc = MFMA16(pa1, ones, lacc, 0, 0, 0);
        __builtin_amdgcn_s_setprio(0);
    }

    // epilogue: lacc[r] IS l for q = quad*4+r (C/D layout row = quad*4+reg)
#pragma unroll
    for (int j = 0; j < 4; j++)
#pragma unroll
        for (int r = 0; r < 4; r++) {
            int s = qt * 64 + w * 16 + quad * 4 + r;
            out[(size_t)(b * 2048 + s) * 1024 + h * 64 + j * 16 + li] =
                o[j][r] / lacc[r];
        }
}

// ---------------------------------------------------------------------------
extern "C" void kernel_launch(void* const* d_in, const int* in_sizes, int n_in,
                              void* d_out, int out_size, void* d_ws, size_t ws_size,
                              hipStream_t stream)
{
    (void)in_sizes; (void)n_in; (void)out_size; (void)ws_size;
    const float* x   = (const float*)d_in[0];   // (2,2048,1024) f32
    const float* wq  = (const float*)d_in[1];   // (1024,1024)  f32
    const float* wkv = (const float*)d_in[2];   // (2048,1024)  f32
    // d_in[3] = causal mask — computed analytically

    ushort* xb = (ushort*)d_ws;                       // 4096x1024 bf16
    ushort* wb = xb + (size_t)4096 * 1024;            // 3072x1024 bf16
    float2* tab = (float2*)(wb + (size_t)3072 * 1024); // 2048x32 (cos,sin)
    ushort* Qb = (ushort*)(tab + 65536);              // (B,H,S,Hd) pre-scaled by C
    ushort* Kb = Qb + (size_t)2 * 16 * 2048 * 64;     // (B,H,S,Hd)
    ushort* Vt = Kb + (size_t)2 * 16 * 2048 * 64;     // (B,H,Hd,S)
    float* out = (float*)d_out;                       // f32 output

    cvt_rope<<<3840, 256, 0, stream>>>(x, wq, wkv, xb, wb, tab);
    dim3 g1(32, 24);
    gemm_qkv<<<g1, 256, 0, stream>>>(xb, wb, tab, Qb, Kb, Vt);
    dim3 g4(32, 32);
    attn<<<g4, 256, 0, stream>>>(Qb, Kb, Vt, out);
}

// Round 17
// 168.267 us; speedup vs baseline: 1.0687x; 1.0244x over previous
//
#include <hip/hip_runtime.h>
#include <hip/hip_bf16.h>
#include <math.h>

// ---------------------------------------------------------------------------
// CausalSelfAttention: B=2, S=2048, D=1024, H=16, Hd=64. f32 in / f32 out.
// R32 = R31 (attn: pinned+balanced+ones-lsum, <=48us; fused cvt_rope) with
// gemm retiled BM 128->64 (BN=128, BK=64 unchanged). gemm was the new top
// dispatch (57.9us) and latency-bound at 3 blocks/CU GRID-capped (MfmaUtil
// 16.8 = 3 blocks x 465cyc MFMA / 2900cyc step; nothing saturated). 1536
// blocks = 6/CU, LDS 24KB (6 fit), acc halves -> VGPR ~85: doubles resident
// blocks so per-iteration stage-drains overlap across blocks (m114).
// Staging: 192 rows [A64|B128] = 6 wave-uniform gl_lds calls/wave, same
// row&7 XOR swizzle. Epilogue per-column math unchanged (BN same -> K-RoPE
// hd+-32 pairing within-tile). T1: XCD c owns m-tiles [8c,8c+8) x all nt.
// ---------------------------------------------------------------------------

typedef short bfrag __attribute__((ext_vector_type(8)));   // 8 bf16 = 4 VGPR
typedef float f32x4 __attribute__((ext_vector_type(4)));

__device__ __forceinline__ float bf2f(ushort u) {
    union { uint i; float f; } v; v.i = ((uint)u) << 16; return v.f;
}
__device__ __forceinline__ ushort f2bf(float f) {
    union { uint i; float f; } v; v.f = f;
    uint u = v.i;
    return (ushort)((u + 0x7fffu + ((u >> 16) & 1u)) >> 16);  // RNE
}
__device__ __forceinline__ ushort f2bf_hw(float f) {
    union { __hip_bfloat16 b; ushort u; } cv;
    cv.b = __float2bfloat16(f);                 // native cvt on gfx950 (RNE)
    return cv.u;
}

#define MFMA16 __builtin_amdgcn_mfma_f32_16x16x32_bf16

__device__ __forceinline__ void gl_lds16(const ushort* g, ushort* l) {
    __builtin_amdgcn_global_load_lds(
        (const __attribute__((address_space(1))) void*)g,
        (__attribute__((address_space(3))) void*)l, 16, 0, 0);
}

// ---------------------------------------------------------------------------
// Kernel 0: fused f32->bf16 convert + rope table.
// Blocks [0,3584): cvt (xb = x; wb = [Wq;Wkv]). Blocks [3584,3840): rope.
// ---------------------------------------------------------------------------
__global__ __launch_bounds__(256)
void cvt_rope(const float* __restrict__ x, const float* __restrict__ wq,
              const float* __restrict__ wkv, ushort* __restrict__ xb,
              ushort* __restrict__ wb, float2* __restrict__ tab)
{
    if (blockIdx.x >= 3584) {
        // rope table: tab[s][fi] = (cos,sin)(s * 10000^(-fi/32))
        int t  = ((int)blockIdx.x - 3584) * 256 + threadIdx.x;   // 65536
        int fi = t & 31, s = t >> 5;
        float invf = (float)exp((double)fi * -0.28782313662425574);
        float thf  = (float)s * invf;
        const double TWO_PI = 6.283185307179586476925287;
        double th = (double)thf;
        double kq = __builtin_rint(th * (1.0 / TWO_PI));
        float r = (float)(th - kq * TWO_PI);
        tab[t] = make_float2(cosf(r), sinf(r));
        return;
    }
    const size_t NX = 4096u * 1024u, NWQ = 1024u * 1024u;
    size_t i8 = ((size_t)blockIdx.x * 256 + threadIdx.x) * 8;
    const float* src;
    ushort* dst;
    if (i8 < NX) { src = x + i8; dst = xb + i8; }
    else {
        size_t j = i8 - NX;
        dst = wb + j;
        src = (j < NWQ) ? (wq + j) : (wkv + (j - NWQ));
    }
    float4 a = *(const float4*)(src);
    float4 c = *(const float4*)(src + 4);
    ushort u[8];
    u[0] = f2bf(a.x); u[1] = f2bf(a.y); u[2] = f2bf(a.z); u[3] = f2bf(a.w);
    u[4] = f2bf(c.x); u[5] = f2bf(c.y); u[6] = f2bf(c.z); u[7] = f2bf(c.w);
    *(uint4*)dst = *(uint4*)u;
}

// ---------------------------------------------------------------------------
// Kernel 1 (R32): QKV GEMM, BM=64 x BN=128, BK=64, swizzled LDS, fused RoPE
// (Q pre-scaled by C), T1 XCD swizzle. 1536 blocks = 6/CU.
// Staging: 192 rows [A(64) | B(128)]; wave w call cc stages 8 rows at
// row_base = w*48 + cc*8 (wave-uniform; groups never straddle the A/B seam).
// ---------------------------------------------------------------------------
__global__ __launch_bounds__(256)
void gemm_qkv(const ushort* __restrict__ xb, const ushort* __restrict__ wb,
              const float2* __restrict__ tab, ushort* __restrict__ Qb,
              ushort* __restrict__ Kb, ushort* __restrict__ Vt)
{
    __shared__ ushort Ash[64][64];
    __shared__ ushort Bsh[128][64];

    const int tid  = threadIdx.x;
    const int lane = tid & 63, wv = tid >> 6;
    const int quad = lane >> 4, li = lane & 15;

    // T1 XCD-aware remap: XCD c owns m-tiles [8c, 8c+8), all 24 n-tiles.
    const int lin = (int)blockIdx.y * 64 + (int)blockIdx.x;   // 0..1535
    const int xc  = lin & 7, idx = lin >> 3;                  // idx 0..191
    const int m0  = (xc * 8 + (idx & 7)) * 64;
    const int n0  = (idx >> 3) * 128;

    f32x4 acc[8];
#pragma unroll
    for (int j = 0; j < 8; j++) acc[j] = (f32x4){0.f, 0.f, 0.f, 0.f};

    const int r8  = lane >> 3;
    const int gch = ((lane & 7) ^ r8) * 8;

    for (int k0 = 0; k0 < 1024; k0 += 64) {
        __syncthreads();
#pragma unroll
        for (int cc = 0; cc < 6; cc++) {
            int rb = wv * 48 + cc * 8;          // wave-uniform row base
            if (rb < 64) {
                gl_lds16(xb + (size_t)(m0 + rb + r8) * 1024 + gch + k0,
                         &Ash[rb][0]);
            } else {
                gl_lds16(wb + (size_t)(n0 + rb - 64 + r8) * 1024 + gch + k0,
                         &Bsh[rb - 64][0]);
            }
        }
        __syncthreads();

        const int sw = li & 7;
#pragma unroll
        for (int ks = 0; ks < 2; ks++) {
            bfrag af = *(const bfrag*)
                &Ash[wv * 16 + li][(((ks << 2) | quad) ^ sw) * 8];
            bfrag bf[8];
#pragma unroll
            for (int j = 0; j < 8; j++)
                bf[j] = *(const bfrag*)
                    &Bsh[j * 16 + li][(((ks << 2) | quad) ^ sw) * 8];
#pragma unroll
            for (int j = 0; j < 8; j++)
                acc[j] = MFMA16(af, bf[j], acc[j], 0, 0, 0);
        }
    }

    if (n0 < 1024) {
        const float CS = 0.125f * 1.4426950408889634f;   // folded softmax scale
        const int hbase = n0 >> 6;
#pragma unroll
        for (int r = 0; r < 4; r++) {
            int m = m0 + wv * 16 + quad * 4 + r;
            int bb = m >> 11, s = m & 2047;
            float2 t0 = tab[s * 32 + li];
            float2 t1 = tab[s * 32 + li + 16];
#pragma unroll
            for (int j = 0; j < 8; j++) {
                float v  = acc[j][r];
                float vp = acc[j ^ 2][r];
                float2 tt = (j & 1) ? t1 : t0;
                float rh = (j & 2) ? vp : -vp;
                int h = hbase + (j >> 2), hd = (j & 3) * 16 + li;
                Qb[(size_t)((bb * 16 + h) * 2048 + s) * 64 + hd] =
                    f2bf((v * tt.x + rh * tt.y) * CS);
            }
        }
    } else {
        const int h = (n0 - 1024) >> 7;
        const int li2 = li >> 1;
        if ((li & 1) == 0) {
#pragma unroll
            for (int r = 0; r < 4; r++) {
                int m = m0 + wv * 16 + quad * 4 + r;
                int bb = m >> 11, s = m & 2047;
                float2 tt4[4];
#pragma unroll
                for (int jj = 0; jj < 4; jj++)
                    tt4[jj] = tab[s * 32 + jj * 8 + li2];
#pragma unroll
                for (int j = 0; j < 8; j++) {
                    float v  = acc[j][r];
                    float vp = acc[j ^ 4][r];
                    float2 tt = tt4[j & 3];
                    float rh = (j & 4) ? vp : -vp;
                    int hd = j * 8 + li2;
                    Kb[(size_t)((bb * 16 + h) * 2048 + s) * 64 + hd] =
                        f2bf(v * tt.x + rh * tt.y);
                }
            }
        } else {
            int m4 = m0 + wv * 16 + quad * 4;
            int bb = m4 >> 11, s0 = m4 & 2047;
#pragma unroll
            for (int j = 0; j < 8; j++) {
                int hd = j * 8 + li2;
                ushort u4[4];
#pragma unroll
                for (int r = 0; r < 4; r++) u4[r] = f2bf(acc[j][r]);
                *(ushort4*)&Vt[(size_t)((bb * 16 + h) * 64 + hd) * 2048 + s0] =
                    *(ushort4*)u4;
            }
        }
    }
}

// ---------------------------------------------------------------------------
// Kernel 2 (R31, verbatim): causal flash attention, swapped-QK^T. Head->XCD
// pinned: bh = (lin&7)*4 + ((lin>>3)&3); u = lin>>5 -> coset sigma ->
// per-CU work = 66 exactly. Q pre-scaled by C; P = exp2(sc); l via
// ones-column MFMA. Two-barrier staging, incremented-pointer prefetch.
// ---------------------------------------------------------------------------
__global__ __launch_bounds__(256)
void attn(const ushort* __restrict__ Qb, const ushort* __restrict__ Kb,
          const ushort* __restrict__ Vt, float* __restrict__ out)
{
    __shared__ ushort Ksh[64][72];
    __shared__ ushort Vsh[64][72];
    __shared__ ushort Psh[4][16][72];

    const int tid  = threadIdx.x;
    const int lane = tid & 63, w = tid >> 6;
    const int quad = lane >> 4, li = lane & 15;

    // head/XCD pinning + coset-balanced q-tile assignment
    const int lin = (int)blockIdx.y * 32 + (int)blockIdx.x;
    const int bh  = (lin & 7) * 4 + ((lin >> 3) & 3);
    const int u   = lin >> 5;
    const int cj = u & 7, ci = u >> 3;
    const int qt = (ci == 0) ? cj : (ci == 1) ? (15 - cj)
                 : (ci == 2) ? (16 + cj) : (31 - cj);

    const int b = bh >> 4, h = bh & 15;

    const int qrow = qt * 64 + w * 16 + li;      // this lane's q (swapped layout)
    const ushort* qp = Qb + (size_t)(bh * 2048 + qrow) * 64;
    bfrag qa0 = *(const bfrag*)(qp + quad * 8);
    bfrag qa1 = *(const bfrag*)(qp + quad * 8 + 32);

    // ones B-fragment (bf16 1.0 = 0x3F80) for the l-sum MFMA
    union { ushort s[8]; bfrag f; } onesu;
#pragma unroll
    for (int i = 0; i < 8; i++) onesu.s[i] = 0x3F80;
    const bfrag ones = onesu.f;

    f32x4 o[4];
#pragma unroll
    for (int j = 0; j < 4; j++) o[j] = (f32x4){0.f, 0.f, 0.f, 0.f};
    f32x4 lacc = (f32x4){0.f, 0.f, 0.f, 0.f};   // l for q=quad*4+r in reg r

    const int srow = tid >> 2, sc0 = (tid & 3) * 16;
    const ushort* kbase = Kb + (size_t)bh * 2048 * 64;
    const ushort* vbase = Vt + (size_t)bh * 64 * 2048;

    // preload kt=0; prefetch pointers advance incrementally (no per-iter mul)
    uint4 ka, kb_, va, vb_;
    const ushort* gkp = kbase + (size_t)(64 + srow) * 64 + sc0;      // tile 1 K
    const ushort* gvp = vbase + (size_t)srow * 2048 + 64 + sc0;      // tile 1 V
    {
        const ushort* gk = kbase + (size_t)srow * 64 + sc0;
        ka  = *(const uint4*)gk;
        kb_ = *(const uint4*)(gk + 8);
        const ushort* gv = vbase + (size_t)srow * 2048 + sc0;
        va  = *(const uint4*)gv;
        vb_ = *(const uint4*)(gv + 8);
    }

    for (int kt = 0; kt <= qt; ++kt) {
        __syncthreads();
        *(uint4*)&Ksh[srow][sc0]     = ka;
        *(uint4*)&Ksh[srow][sc0 + 8] = kb_;
        *(uint4*)&Vsh[srow][sc0]     = va;
        *(uint4*)&Vsh[srow][sc0 + 8] = vb_;
        __syncthreads();

        if (kt < qt) {     // prefetch next tile; latency hidden by compute
            ka  = *(const uint4*)gkp;
            kb_ = *(const uint4*)(gkp + 8);
            va  = *(const uint4*)gvp;
            vb_ = *(const uint4*)(gvp + 8);
            gkp += 64 * 64;          // next K tile (64 rows x 64 hd)
            gvp += 64;               // next V tile (64 s-cols)
        }

        // --- scores (pre-scaled): sc[j][r] = C*S[k=kt*64+j*16+quad*4+r][q=li] ---
        f32x4 sc[4];
        __builtin_amdgcn_s_setprio(1);
#pragma unroll
        for (int j = 0; j < 4; j++) {
            bfrag kb0 = *(const bfrag*)&Ksh[j * 16 + li][quad * 8];
            bfrag kb1 = *(const bfrag*)&Ksh[j * 16 + li][quad * 8 + 32];
            f32x4 z = (f32x4){0.f, 0.f, 0.f, 0.f};
            z = MFMA16(kb0, qa0, z, 0, 0, 0);
            z = MFMA16(kb1, qa1, z, 0, 0, 0);
            sc[j] = z;
        }
        __builtin_amdgcn_s_setprio(0);

        // --- causal mask: only the diagonal tile needs it ---
        if (kt == qt) {
#pragma unroll
            for (int j = 0; j < 4; j++) {
                int kg0 = kt * 64 + j * 16 + quad * 4;
#pragma unroll
                for (int r = 0; r < 4; r++)
                    sc[j][r] = (kg0 + r <= qrow) ? sc[j][r] : -3.0e38f;
            }
        }

        // --- P = exp2(sc), hw RNE to bf16 (row-sum done by ones-MFMA) ---
#pragma unroll
        for (int j = 0; j < 4; j++) {
            ushort pk[4];
#pragma unroll
            for (int r = 0; r < 4; r++)
                pk[r] = f2bf_hw(exp2f(sc[j][r]));
            *(ushort4*)&Psh[w][li][j * 16 + quad * 4] = *(ushort4*)pk;
        }

        // --- P: LDS -> A-fragment (wave-private Psh) ---
        asm volatile("s_waitcnt lgkmcnt(0)" ::: "memory");
        bfrag pa0 = *(const bfrag*)&Psh[w][li][quad * 8];
        bfrag pa1 = *(const bfrag*)&Psh[w][li][quad * 8 + 32];

        __builtin_amdgcn_s_setprio(1);
#pragma unroll
        for (int j = 0; j < 4; j++) {
            bfrag vb0 = *(const bfrag*)&Vsh[j * 16 + li][quad * 8];
            bfrag vb1 = *(const bfrag*)&Vsh[j * 16 + li][quad * 8 + 32];
            o[j] = MFMA16(pa0, vb0, o[j], 0, 0, 0);
            o[j] = MFMA16(pa1, vb1, o[j], 0, 0, 0);
        }
        // l-sum on the matrix pipe: lacc[r] += sum_k P[k][q=quad*4+r]
        lacc = MFMA16(pa0, ones, lacc, 0, 0, 0);
        lacc = MFMA16(pa1, ones, lacc, 0, 0, 0);
        __builtin_amdgcn_s_setprio(0);
    }

    // epilogue: lacc[r] IS l for q = quad*4+r (C/D layout row = quad*4+reg)
#pragma unroll
    for (int j = 0; j < 4; j++)
#pragma unroll
        for (int r = 0; r < 4; r++) {
            int s = qt * 64 + w * 16 + quad * 4 + r;
            out[(size_t)(b * 2048 + s) * 1024 + h * 64 + j * 16 + li] =
                o[j][r] / lacc[r];
        }
}

// ---------------------------------------------------------------------------
extern "C" void kernel_launch(void* const* d_in, const int* in_sizes, int n_in,
                              void* d_out, int out_size, void* d_ws, size_t ws_size,
                              hipStream_t stream)
{
    (void)in_sizes; (void)n_in; (void)out_size; (void)ws_size;
    const float* x   = (const float*)d_in[0];   // (2,2048,1024) f32
    const float* wq  = (const float*)d_in[1];   // (1024,1024)  f32
    const float* wkv = (const float*)d_in[2];   // (2048,1024)  f32
    // d_in[3] = causal mask — computed analytically

    ushort* xb = (ushort*)d_ws;                       // 4096x1024 bf16
    ushort* wb = xb + (size_t)4096 * 1024;            // 3072x1024 bf16
    float2* tab = (float2*)(wb + (size_t)3072 * 1024); // 2048x32 (cos,sin)
    ushort* Qb = (ushort*)(tab + 65536);              // (B,H,S,Hd) pre-scaled by C
    ushort* Kb = Qb + (size_t)2 * 16 * 2048 * 64;     // (B,H,S,Hd)
    ushort* Vt = Kb + (size_t)2 * 16 * 2048 * 64;     // (B,H,Hd,S)
    float* out = (float*)d_out;                       // f32 output

    cvt_rope<<<3840, 256, 0, stream>>>(x, wq, wkv, xb, wb, tab);
    dim3 g1(64, 24);
    gemm_qkv<<<g1, 256, 0, stream>>>(xb, wb, tab, Qb, Kb, Vt);
    dim3 g4(32, 32);
    attn<<<g4, 256, 0, stream>>>(Qb, Kb, Vt, out);
}